// Round 1
// baseline (99.513 us; speedup 1.0000x reference)
//
#include <hip/hip_runtime.h>

#define N 2048
#define COLSTRIDE 64   // max nonzeros per adjacency column we record (actual ~17)

// ---- block-wide exclusive scan over 256 threads (4 waves of 64) ----
__device__ __forceinline__ void block_scan_256(int cnt, int tid, int* excl_out,
                                               int* total_out, int* wsum /*LDS[4]*/) {
    int lane = tid & 63, wave = tid >> 6;
    int incl = cnt;
    #pragma unroll
    for (int d = 1; d < 64; d <<= 1) {
        int v = __shfl_up(incl, d, 64);
        if (lane >= d) incl += v;
    }
    if (lane == 63) wsum[wave] = incl;
    __syncthreads();
    int wbase = 0;
    #pragma unroll
    for (int w = 0; w < 4; ++w) { if (w < wave) wbase += wsum[w]; }
    *excl_out  = wbase + incl - cnt;
    *total_out = wsum[0] + wsum[1] + wsum[2] + wsum[3];
}

// ---- kernel 1: per-row scan of adjacency; emit R(i) and per-column (i, rank) records ----
__global__ __launch_bounds__(256) void rowscan_kernel(const float* __restrict__ adj,
                                                      int* __restrict__ R,
                                                      int* __restrict__ colCnt,
                                                      int* __restrict__ colList) {
    __shared__ int wsum[4];
    int i = blockIdx.x, tid = threadIdx.x;
    const float4* rp = (const float4*)(adj + (size_t)i * N);
    float4 v0 = rp[tid * 2], v1 = rp[tid * 2 + 1];
    float v[8] = {v0.x, v0.y, v0.z, v0.w, v1.x, v1.y, v1.z, v1.w};
    int cnt = 0;
    #pragma unroll
    for (int e = 0; e < 8; ++e) cnt += (v[e] != 0.0f) ? 1 : 0;
    int base, total;
    block_scan_256(cnt, tid, &base, &total, wsum);
    int rank = base;  // in-row rank t of each nonzero, in column order
    #pragma unroll
    for (int e = 0; e < 8; ++e) {
        if (v[e] != 0.0f) {
            int j = tid * 8 + e;
            int slot = atomicAdd(&colCnt[j], 1);
            if (slot < COLSTRIDE) colList[j * COLSTRIDE + slot] = i | (rank << 16);
            rank++;
        }
    }
    if (tid == 0) R[i] = total;
}

// ---- kernel 2: exclusive prefix sum of R -> P ----
__global__ __launch_bounds__(256) void scan_kernel(const int* __restrict__ R,
                                                   int* __restrict__ P) {
    __shared__ int wsum[4];
    int tid = threadIdx.x;
    int vals[8]; int cnt = 0;
    #pragma unroll
    for (int e = 0; e < 8; ++e) { vals[e] = R[tid * 8 + e]; cnt += vals[e]; }
    int base, total;
    block_scan_256(cnt, tid, &base, &total, wsum);
    int run = base;
    #pragma unroll
    for (int e = 0; e < 8; ++e) { P[tid * 8 + e] = run; run += vals[e]; }
    (void)total;
}

// ---- kernel 3: transpose inputs (viewed as [128][2048], ba-major) -> inT[2048][128] ----
__global__ __launch_bounds__(256) void transpose_kernel(const float* __restrict__ in2,
                                                        float* __restrict__ inT) {
    __shared__ float tile[32][33];
    int x  = blockIdx.x * 32 + threadIdx.x;   // i (coalesced read)
    int y0 = blockIdx.y * 32;                 // ba tile
    #pragma unroll
    for (int r = 0; r < 32; r += 8)
        tile[threadIdx.y + r][threadIdx.x] = in2[(y0 + threadIdx.y + r) * N + x];
    __syncthreads();
    int xo  = y0 + threadIdx.x;               // ba (coalesced write)
    int yo0 = blockIdx.x * 32;                // i tile
    #pragma unroll
    for (int r = 0; r < 32; r += 8)
        inT[(yo0 + threadIdx.y + r) * 128 + xo] = tile[threadIdx.x][threadIdx.y + r];
}

// ---- kernel 4: gather per output column j; thread = (b, c) ----
__global__ __launch_bounds__(128) void gather_kernel(const float* __restrict__ inT,
                                                     const float* __restrict__ kern,
                                                     const float* __restrict__ bias,
                                                     const int* __restrict__ R,
                                                     const int* __restrict__ P,
                                                     const int* __restrict__ colCnt,
                                                     const int* __restrict__ colList,
                                                     float* __restrict__ out, int NNZ) {
    __shared__ int s_i[COLSTRIDE], s_t[COLSTRIDE], s_r[COLSTRIDE], s_p[COLSTRIDE];
    int j = blockIdx.x, tid = threadIdx.x;
    int b = tid >> 2, c = tid & 3;
    int cnt = colCnt[j]; if (cnt > COLSTRIDE) cnt = COLSTRIDE;
    if (tid < cnt) {
        int rec = colList[j * COLSTRIDE + tid];
        int i = rec & 0xFFFF, t = rec >> 16;
        s_i[tid] = i; s_t[tid] = t; s_r[tid] = R[i]; s_p[tid] = P[i];
    }
    __syncthreads();
    int NNZ4 = 4 * NNZ;
    float acc = bias[c * N + j];
    for (int k = 0; k < cnt; ++k) {
        int i = s_i[k];
        const float4 x = *(const float4*)(inT + i * 128 + b * 4);  // in[b, a=0..3, i]
        int wb = 4 * s_p[k] + c * s_r[k] + s_t[k];
        acc += x.x * kern[wb] + x.y * kern[wb + NNZ4]
             + x.z * kern[wb + 2 * NNZ4] + x.w * kern[wb + 3 * NNZ4];
    }
    out[b * (4 * N) + c * N + j] = acc;
}

extern "C" void kernel_launch(void* const* d_in, const int* in_sizes, int n_in,
                              void* d_out, int out_size, void* d_ws, size_t ws_size,
                              hipStream_t stream) {
    const float* inputs = (const float*)d_in[0];   // (32, 8192)
    const float* adj    = (const float*)d_in[1];   // (2048, 2048)
    const float* kern   = (const float*)d_in[2];   // (16 * NNZ,)
    const float* bias   = (const float*)d_in[3];   // (8192,)
    float* out = (float*)d_out;                    // (32, 8192) fp32
    int NNZ = in_sizes[2] / 16;                    // channels * in_chan = 16

    // ws layout (ints):  R[2048] | P[2048] | colCnt[2048] | colList[2048*64] | inT (floats)
    int*   wsR     = (int*)d_ws;
    int*   wsP     = wsR + 2048;
    int*   colCnt  = wsR + 4096;
    int*   colList = wsR + 6144;                   // ends at 6144 + 131072 = 137216
    float* inT     = (float*)(wsR + 137216);       // 2048*128 floats; 16B aligned

    hipMemsetAsync(colCnt, 0, N * sizeof(int), stream);
    rowscan_kernel<<<N, 256, 0, stream>>>(adj, wsR, colCnt, colList);
    scan_kernel<<<1, 256, 0, stream>>>(wsR, wsP);
    transpose_kernel<<<dim3(64, 4), dim3(32, 8), 0, stream>>>(inputs, inT);
    gather_kernel<<<N, 128, 0, stream>>>(inT, kern, bias, wsR, wsP, colCnt, colList, out, NNZ);
}

// Round 2
// 98.065 us; speedup vs baseline: 1.0148x; 1.0148x over previous
//
#include <hip/hip_runtime.h>

#define N 2048
#define COLSTRIDE 64   // max nonzeros per adjacency column we record (actual ~17, max ~40)

// ---- block-wide exclusive scan over 256 threads (4 waves of 64) ----
__device__ __forceinline__ void block_scan_256(int cnt, int tid, int* excl_out,
                                               int* total_out, int* wsum /*LDS[4]*/) {
    int lane = tid & 63, wave = tid >> 6;
    int incl = cnt;
    #pragma unroll
    for (int d = 1; d < 64; d <<= 1) {
        int v = __shfl_up(incl, d, 64);
        if (lane >= d) incl += v;
    }
    if (lane == 63) wsum[wave] = incl;
    __syncthreads();
    int wbase = 0;
    #pragma unroll
    for (int w = 0; w < 4; ++w) { if (w < wave) wbase += wsum[w]; }
    *excl_out  = wbase + incl - cnt;
    *total_out = wsum[0] + wsum[1] + wsum[2] + wsum[3];
}

// ---- fused kernel: blocks 0..2047 = per-row adjacency scan; blocks 2048..2303 = input transpose ----
__global__ __launch_bounds__(256) void prep_kernel(const float* __restrict__ adj,
                                                   const float* __restrict__ in2,
                                                   int* __restrict__ R,
                                                   int* __restrict__ colCnt,
                                                   int* __restrict__ colList,
                                                   float* __restrict__ inT) {
    __shared__ int wsum[4];
    __shared__ float tile[32][33];
    int tid = threadIdx.x;
    if (blockIdx.x < N) {
        // --- rowscan: emit R(i) and per-column (i, rank) records ---
        int i = blockIdx.x;
        const float4* rp = (const float4*)(adj + (size_t)i * N);
        float4 v0 = rp[tid * 2], v1 = rp[tid * 2 + 1];
        float v[8] = {v0.x, v0.y, v0.z, v0.w, v1.x, v1.y, v1.z, v1.w};
        int cnt = 0;
        #pragma unroll
        for (int e = 0; e < 8; ++e) cnt += (v[e] != 0.0f) ? 1 : 0;
        int base, total;
        block_scan_256(cnt, tid, &base, &total, wsum);
        int rank = base;  // in-row rank t of each nonzero, in column order
        #pragma unroll
        for (int e = 0; e < 8; ++e) {
            if (v[e] != 0.0f) {
                int j = tid * 8 + e;
                int slot = atomicAdd(&colCnt[j], 1);
                if (slot < COLSTRIDE) colList[j * COLSTRIDE + slot] = i | (rank << 16);
                rank++;
            }
        }
        if (tid == 0) R[i] = total;
    } else {
        // --- transpose inputs (viewed as [128][2048], ba-major) -> inT[2048][128] ---
        int id = blockIdx.x - N;
        int bx = id & 63, by = id >> 6;          // bx: i-tile (64), by: ba-tile (4)
        int tx = tid & 31, ty = tid >> 5;        // 32x8 threads
        int x  = bx * 32 + tx;                   // i (coalesced read)
        int y0 = by * 32;                        // ba tile base
        #pragma unroll
        for (int r = 0; r < 32; r += 8)
            tile[ty + r][tx] = in2[(y0 + ty + r) * N + x];
        __syncthreads();
        #pragma unroll
        for (int r = 0; r < 32; r += 8)
            inT[(bx * 32 + ty + r) * 128 + y0 + tx] = tile[tx][ty + r];
    }
}

// ---- kernel 2: exclusive prefix sum of R -> P ----
__global__ __launch_bounds__(256) void scan_kernel(const int* __restrict__ R,
                                                   int* __restrict__ P) {
    __shared__ int wsum[4];
    int tid = threadIdx.x;
    int vals[8]; int cnt = 0;
    #pragma unroll
    for (int e = 0; e < 8; ++e) { vals[e] = R[tid * 8 + e]; cnt += vals[e]; }
    int base, total;
    block_scan_256(cnt, tid, &base, &total, wsum);
    int run = base;
    #pragma unroll
    for (int e = 0; e < 8; ++e) { P[tid * 8 + e] = run; run += vals[e]; }
    (void)total;
}

// ---- kernel 3: gather per output column j; thread = (b, c) ----
__global__ __launch_bounds__(128) void gather_kernel(const float* __restrict__ inT,
                                                     const float* __restrict__ kern,
                                                     const float* __restrict__ bias,
                                                     const int* __restrict__ R,
                                                     const int* __restrict__ P,
                                                     const int* __restrict__ colCnt,
                                                     const int* __restrict__ colList,
                                                     float* __restrict__ out, int NNZ) {
    __shared__ int s_i[COLSTRIDE], s_t[COLSTRIDE], s_r[COLSTRIDE], s_p[COLSTRIDE];
    int j = blockIdx.x, tid = threadIdx.x;
    int b = tid >> 2, c = tid & 3;
    int cnt = colCnt[j]; if (cnt > COLSTRIDE) cnt = COLSTRIDE;
    if (tid < cnt) {
        int rec = colList[j * COLSTRIDE + tid];
        int i = rec & 0xFFFF, t = rec >> 16;
        s_i[tid] = i; s_t[tid] = t; s_r[tid] = R[i]; s_p[tid] = P[i];
    }
    __syncthreads();
    int NNZ4 = 4 * NNZ;
    float acc = bias[c * N + j];
    for (int k = 0; k < cnt; ++k) {
        int i = s_i[k];
        const float4 x = *(const float4*)(inT + i * 128 + b * 4);  // in[b, a=0..3, i]
        int wb = 4 * s_p[k] + c * s_r[k] + s_t[k];
        acc += x.x * kern[wb] + x.y * kern[wb + NNZ4]
             + x.z * kern[wb + 2 * NNZ4] + x.w * kern[wb + 3 * NNZ4];
    }
    out[b * (4 * N) + c * N + j] = acc;
}

extern "C" void kernel_launch(void* const* d_in, const int* in_sizes, int n_in,
                              void* d_out, int out_size, void* d_ws, size_t ws_size,
                              hipStream_t stream) {
    const float* inputs = (const float*)d_in[0];   // (32, 8192)
    const float* adj    = (const float*)d_in[1];   // (2048, 2048)
    const float* kern   = (const float*)d_in[2];   // (16 * NNZ,)
    const float* bias   = (const float*)d_in[3];   // (8192,)
    float* out = (float*)d_out;                    // (32, 8192) fp32
    int NNZ = in_sizes[2] / 16;                    // channels * in_chan = 16

    // ws layout (ints):  R[2048] | P[2048] | colCnt[2048] | colList[2048*64] | inT (floats)
    int*   wsR     = (int*)d_ws;
    int*   wsP     = wsR + 2048;
    int*   colCnt  = wsR + 4096;
    int*   colList = wsR + 6144;                   // ends at 6144 + 131072 = 137216
    float* inT     = (float*)(wsR + 137216);       // 2048*128 floats; 16B aligned

    hipMemsetAsync(colCnt, 0, N * sizeof(int), stream);
    prep_kernel<<<N + 256, 256, 0, stream>>>(adj, inputs, wsR, colCnt, colList, inT);
    scan_kernel<<<1, 256, 0, stream>>>(wsR, wsP);
    gather_kernel<<<N, 128, 0, stream>>>(inT, kern, bias, wsR, wsP, colCnt, colList, out, NNZ);
}

// Round 3
// 97.892 us; speedup vs baseline: 1.0166x; 1.0018x over previous
//
#include <hip/hip_runtime.h>

#define N 2048
#define COLSTRIDE 64   // max nonzeros per adjacency column we record (actual ~17, max ~40)

// ---- block-wide exclusive scan over 256 threads (4 waves of 64) ----
__device__ __forceinline__ void block_scan_256(int cnt, int tid, int* excl_out,
                                               int* total_out, int* wsum /*LDS[4]*/) {
    int lane = tid & 63, wave = tid >> 6;
    int incl = cnt;
    #pragma unroll
    for (int d = 1; d < 64; d <<= 1) {
        int v = __shfl_up(incl, d, 64);
        if (lane >= d) incl += v;
    }
    if (lane == 63) wsum[wave] = incl;
    __syncthreads();
    int wbase = 0;
    #pragma unroll
    for (int w = 0; w < 4; ++w) { if (w < wave) wbase += wsum[w]; }
    *excl_out  = wbase + incl - cnt;
    *total_out = wsum[0] + wsum[1] + wsum[2] + wsum[3];
}

// ---- fused kernel: blocks 0..2047 = per-row adjacency scan; blocks 2048..2303 = input transpose ----
__global__ __launch_bounds__(256) void prep_kernel(const float* __restrict__ adj,
                                                   const float* __restrict__ in2,
                                                   int* __restrict__ R,
                                                   int* __restrict__ colCnt,
                                                   int* __restrict__ colList,
                                                   float* __restrict__ inT) {
    __shared__ int wsum[4];
    __shared__ float tile[32][33];
    int tid = threadIdx.x;
    if (blockIdx.x < N) {
        // --- rowscan: emit R(i) and per-column (i, rank) records ---
        int i = blockIdx.x;
        const float4* rp = (const float4*)(adj + (size_t)i * N);
        float4 v0 = rp[tid * 2], v1 = rp[tid * 2 + 1];
        float v[8] = {v0.x, v0.y, v0.z, v0.w, v1.x, v1.y, v1.z, v1.w};
        int cnt = 0;
        #pragma unroll
        for (int e = 0; e < 8; ++e) cnt += (v[e] != 0.0f) ? 1 : 0;
        int base, total;
        block_scan_256(cnt, tid, &base, &total, wsum);
        int rank = base;  // in-row rank t of each nonzero, in column order
        #pragma unroll
        for (int e = 0; e < 8; ++e) {
            if (v[e] != 0.0f) {
                int j = tid * 8 + e;
                int slot = atomicAdd(&colCnt[j], 1);
                if (slot < COLSTRIDE) colList[j * COLSTRIDE + slot] = i | (rank << 16);
                rank++;
            }
        }
        if (tid == 0) R[i] = total;
    } else {
        // --- transpose inputs (viewed as [128][2048], ba-major) -> inT[2048][128] ---
        int id = blockIdx.x - N;
        int bx = id & 63, by = id >> 6;          // bx: i-tile (64), by: ba-tile (4)
        int tx = tid & 31, ty = tid >> 5;        // 32x8 threads
        int x  = bx * 32 + tx;                   // i (coalesced read)
        int y0 = by * 32;                        // ba tile base
        #pragma unroll
        for (int r = 0; r < 32; r += 8)
            tile[ty + r][tx] = in2[(y0 + ty + r) * N + x];
        __syncthreads();
        #pragma unroll
        for (int r = 0; r < 32; r += 8)
            inT[(bx * 32 + ty + r) * 128 + y0 + tx] = tile[tx][ty + r];
    }
}

// ---- kernel 2: gather per output column j; thread = (b, c); inline exclusive scan of R ----
__global__ __launch_bounds__(128) void gather_kernel(const float* __restrict__ inT,
                                                     const float* __restrict__ kern,
                                                     const float* __restrict__ bias,
                                                     const int* __restrict__ R,
                                                     const int* __restrict__ colCnt,
                                                     const int* __restrict__ colList,
                                                     float* __restrict__ out, int NNZ) {
    __shared__ int s_i[COLSTRIDE], s_t[COLSTRIDE], s_rr[COLSTRIDE], s_p[COLSTRIDE];
    __shared__ int E[128];      // exclusive prefix of 16-element chunks of R
    __shared__ int wsum2[2];
    int j = blockIdx.x, tid = threadIdx.x;

    // --- inline exclusive scan: E[tid] = sum of R[0 .. tid*16-1] ---
    const int4* R4 = (const int4*)(R + tid * 16);
    int4 a0 = R4[0], a1 = R4[1], a2 = R4[2], a3 = R4[3];
    int s = a0.x + a0.y + a0.z + a0.w + a1.x + a1.y + a1.z + a1.w
          + a2.x + a2.y + a2.z + a2.w + a3.x + a3.y + a3.z + a3.w;
    int lane = tid & 63, wave = tid >> 6;
    int incl = s;
    #pragma unroll
    for (int d = 1; d < 64; d <<= 1) {
        int v = __shfl_up(incl, d, 64);
        if (lane >= d) incl += v;
    }
    if (lane == 63) wsum2[wave] = incl;
    __syncthreads();
    E[tid] = incl - s + (wave ? wsum2[0] : 0);
    __syncthreads();

    // --- load this column's records; P(i) = E[i>>4] + sum R[chunk_base .. i-1] ---
    int cnt = colCnt[j]; if (cnt > COLSTRIDE) cnt = COLSTRIDE;
    if (tid < cnt) {
        int rec = colList[j * COLSTRIDE + tid];
        int i = rec & 0xFFFF, t = rec >> 16;
        int p = E[i >> 4];
        for (int r = (i >> 4) << 4; r < i; ++r) p += R[r];
        s_i[tid] = i; s_t[tid] = t; s_rr[tid] = R[i]; s_p[tid] = p;
    }
    __syncthreads();

    int b = tid >> 2, c = tid & 3;
    int NNZ4 = 4 * NNZ;
    float acc = bias[c * N + j];
    for (int k = 0; k < cnt; ++k) {
        int i = s_i[k];
        const float4 x = *(const float4*)(inT + i * 128 + b * 4);  // in[b, a=0..3, i]
        int wb = 4 * s_p[k] + c * s_rr[k] + s_t[k];
        acc += x.x * kern[wb] + x.y * kern[wb + NNZ4]
             + x.z * kern[wb + 2 * NNZ4] + x.w * kern[wb + 3 * NNZ4];
    }
    out[b * (4 * N) + c * N + j] = acc;
}

extern "C" void kernel_launch(void* const* d_in, const int* in_sizes, int n_in,
                              void* d_out, int out_size, void* d_ws, size_t ws_size,
                              hipStream_t stream) {
    const float* inputs = (const float*)d_in[0];   // (32, 8192)
    const float* adj    = (const float*)d_in[1];   // (2048, 2048)
    const float* kern   = (const float*)d_in[2];   // (16 * NNZ,)
    const float* bias   = (const float*)d_in[3];   // (8192,)
    float* out = (float*)d_out;                    // (32, 8192) fp32
    int NNZ = in_sizes[2] / 16;                    // channels * in_chan = 16

    // ws layout (ints):  R[2048] | colCnt[2048] | colList[2048*64] | inT (floats)
    int*   wsR     = (int*)d_ws;
    int*   colCnt  = wsR + 2048;
    int*   colList = wsR + 4096;                   // ends at 4096 + 131072 = 135168
    float* inT     = (float*)(wsR + 135168);       // 2048*128 floats; 16B aligned

    hipMemsetAsync(colCnt, 0, N * sizeof(int), stream);
    prep_kernel<<<N + 256, 256, 0, stream>>>(adj, inputs, wsR, colCnt, colList, inT);
    gather_kernel<<<N, 128, 0, stream>>>(inT, kern, bias, wsR, colCnt, colList, out, NNZ);
}